// Round 6
// baseline (423.532 us; speedup 1.0000x reference)
//
#include <hip/hip_runtime.h>

#define NK 8
#define NV 8

// Input layout: inp[b][c][h][w], C = 80, HW = 512*512 contiguous per channel.
// Each thread handles 8 consecutive w (two dwordx4 nt loads per channel).
// All channel accesses perfectly coalesced; per-workgroup contiguity is
// 8KB per channel-plane.
//
// History: R1-R3 all ~441us regardless of unroll/softmax structure ->
// dur_us is kernel + ~325us fixed harness work (d_ws poison fill 205us +
// d_in restore ~106us, visible in rocprof). R5 nt loads/stores: 442->415us,
// first kernel-side win. This round: vec8 per thread (half the waves, 2x
// per-byte addressing efficiency, 2x DRAM contiguity per wg).

typedef float vf8 __attribute__((ext_vector_type(8)));

__device__ __forceinline__ vf8 ntload8(const float* p) {
    return __builtin_nontemporal_load(reinterpret_cast<const vf8*>(p));
}
__device__ __forceinline__ void ntstore8(float* p, vf8 v) {
    __builtin_nontemporal_store(v, reinterpret_cast<vf8*>(p));
}

__global__ __launch_bounds__(256) void dpa_kernel(const float* __restrict__ inp,
                                                  float* __restrict__ out) {
    constexpr int HW = 512 * 512;          // 262144 floats per channel plane
    constexpr int C = NK + NK * NV + NV;   // 80
    const float scale = 0.35355339059327373f; // 1/sqrt(8)

    int idx = blockIdx.x * blockDim.x + threadIdx.x; // one vec8 per thread
    int b  = idx >> 15;          // HW/8 = 32768 vec8's per batch-plane
    int s8 = idx & 32767;
    const float* pin = inp + (size_t)b * C * HW + (size_t)s8 * 8;

    vf8 qk[NV];
#pragma unroll
    for (int v = 0; v < NV; ++v) qk[v] = (vf8)(0.f);

    // qk[v] = sum_k q[k] * K[k][v]; rolled k-loop keeps ~9 vec8 loads in
    // flight (72KB/CU outstanding at 8 waves/CU) without register blowup.
#pragma unroll 1
    for (int kk = 0; kk < NK; ++kk) {
        vf8 qv = ntload8(pin + (size_t)kk * HW);
#pragma unroll
        for (int v = 0; v < NV; ++v) {
            vf8 kv = ntload8(pin + (size_t)(NK + kk * NV + v) * HW);
            qk[v] = qv * kv + qk[v];   // elementwise fma
        }
    }

    // scale
#pragma unroll
    for (int v = 0; v < NV; ++v) qk[v] *= scale;

    // componentwise max over v
    vf8 mx = qk[0];
#pragma unroll
    for (int v = 1; v < NV; ++v) mx = __builtin_elementwise_max(mx, qk[v]);

    // exp and sum (componentwise)
    vf8 sum = (vf8)(0.f);
#pragma unroll
    for (int v = 0; v < NV; ++v) {
#pragma unroll
        for (int c = 0; c < 8; ++c)
            qk[v][c] = __expf(qk[v][c] - mx[c]);
        sum += qk[v];
    }
    vf8 inv = 1.0f / sum;

    // out[b][v][h][w] = softmax * vchan
    float* pout = out + (size_t)b * NV * HW + (size_t)s8 * 8;
#pragma unroll 2
    for (int v = 0; v < NV; ++v) {
        vf8 vv = ntload8(pin + (size_t)(NK + NK * NV + v) * HW);
        ntstore8(pout + (size_t)v * HW, qk[v] * inv * vv);
    }
}

extern "C" void kernel_launch(void* const* d_in, const int* in_sizes, int n_in,
                              void* d_out, int out_size, void* d_ws, size_t ws_size,
                              hipStream_t stream) {
    const float* inp = (const float*)d_in[0];
    float* out = (float*)d_out;

    constexpr int HW = 512 * 512;
    constexpr int C = NK + NK * NV + NV; // 80
    int B = in_sizes[0] / (C * HW);      // 4

    int nThreads = B * (HW / 8);         // one vec8 per thread
    dim3 block(256);
    dim3 grid(nThreads / 256);
    dpa_kernel<<<grid, block, 0, stream>>>(inp, out);
}